// Round 5
// baseline (269.442 us; speedup 1.0000x reference)
//
#include <hip/hip_runtime.h>
#include <stdint.h>

#define IN_DIM  4096
#define OUT_DIM 4096
#define BATCH   4096
#define NACT    32

typedef float f32x4 __attribute__((ext_vector_type(4)));

// ---------------------------------------------------------------------------
// Fused prep kernel.
//   blocks [0, OUT_DIM)              : compress mask+weight -> idx/w tables
//   blocks [OUT_DIM, OUT_DIM+4096)   : transpose x -> xT (64x64 f32 tiles)
// Fusing overlaps their independent memory streams (192 MB total).
// ---------------------------------------------------------------------------
__global__ __launch_bounds__(256)
void prep_kernel(const float* __restrict__ weight,
                 const int*   __restrict__ mask,
                 const float* __restrict__ x,
                 int*         __restrict__ idx_tab,
                 float*       __restrict__ w_tab,
                 float*       __restrict__ xT) {
    __shared__ float tile[64][65];        // transpose tile; aliased as scan[]
    int* scan = (int*)&tile[0][0];
    const int t = threadIdx.x;

    if (blockIdx.x < OUT_DIM) {
        // ---- compress: one block per output row ----
        const int o = blockIdx.x;
        const int* mrow = mask + (size_t)o * IN_DIM;
        const int  base = t * 16;

        int m[16];
        const int4* m4 = (const int4*)(mrow + base);
        #pragma unroll
        for (int j = 0; j < 4; ++j) {
            int4 v = m4[j];
            m[j*4+0] = v.x; m[j*4+1] = v.y; m[j*4+2] = v.z; m[j*4+3] = v.w;
        }
        int c = 0;
        #pragma unroll
        for (int j = 0; j < 16; ++j) c += (m[j] != 0);

        scan[t] = c;
        __syncthreads();
        for (int off = 1; off < 256; off <<= 1) {
            int add = (t >= off) ? scan[t - off] : 0;
            __syncthreads();
            scan[t] += add;
            __syncthreads();
        }
        int pos = scan[t] - c;            // exclusive prefix
        for (int j = 0; j < 16; ++j) {
            if (m[j] != 0) {
                int idx = base + j;
                idx_tab[o * NACT + pos] = idx;
                w_tab [o * NACT + pos] = weight[(size_t)o * IN_DIM + idx];
                ++pos;
            }
        }
    } else {
        // ---- transpose: 64x64 tile ----
        const int q  = blockIdx.x - OUT_DIM;
        const int bi = q & 63;            // batch tile
        const int bj = q >> 6;            // in-dim tile
        {
            const int c  = (t & 15) * 4;
            const int r0 = t >> 4;
            #pragma unroll
            for (int p = 0; p < 4; ++p) {
                int r = r0 + p * 16;
                float4 v = *(const float4*)(x + (size_t)(bi*64 + r) * IN_DIM + bj*64 + c);
                tile[r][c+0] = v.x; tile[r][c+1] = v.y;
                tile[r][c+2] = v.z; tile[r][c+3] = v.w;
            }
        }
        __syncthreads();
        {
            const int b4 = (t & 15) * 4;
            const int j0 = t >> 4;
            #pragma unroll
            for (int p = 0; p < 4; ++p) {
                int j = j0 + p * 16;
                float4 v;
                v.x = tile[b4+0][j]; v.y = tile[b4+1][j];
                v.z = tile[b4+2][j]; v.w = tile[b4+3][j];
                *(float4*)(xT + (size_t)(bj*64 + j) * BATCH + bi*64 + b4) = v;
            }
        }
    }
}

// ---------------------------------------------------------------------------
// Main sparse matmul.
// Thread t = batch (slab*64 + (t>>2)) x output-quad (t&3) -> acc[4].
// Store: lanes 0-3 cover one full 64B line -> wave store = 16 full lines,
// nt-safe (no partial-line write amplification) while bypassing L2 so the
// x-slab (1 MB) stays resident.
// Tables for the 16-output tile in LDS, stride-33 padded (quad reads were
// 4-way same-bank at stride 32).
// Grid = 64 slabs * 256 o-tiles = 16384; swizzle: each XCD sweeps o-tiles
// slab-major (slabs 8x..8x+7).
// ---------------------------------------------------------------------------
__global__ __launch_bounds__(256)
void spmm_kernel(const float* __restrict__ xT,
                 const int*   __restrict__ idx_tab,
                 const float* __restrict__ w_tab,
                 const float* __restrict__ bias,
                 float*       __restrict__ out) {
    const int t   = threadIdx.x;
    const int bid = blockIdx.x;               // 16384 blocks
    const int v    = (bid & 7) * 2048 + (bid >> 3);  // bijective XCD swizzle
    const int slab = v >> 8;                  // 0..63 (slab-major per XCD)
    const int ot   = v & 255;                 // o-tile minor
    const int o0   = ot * 16;
    const int bl   = t >> 2;                  // 0..63 batch-local
    const int oq   = t & 3;                   // output quad
    const int b    = slab * 64 + bl;

    __shared__ int   s_idx[16 * 33];          // stride-33: conflict-free quads
    __shared__ float s_w  [16 * 33];
    __shared__ float s_bias[16];

    // strided preload: 512 idx + 512 w, 2 each per thread
    #pragma unroll
    for (int r = 0; r < 2; ++r) {
        int i = t + r * 256;                  // 0..511
        int row = i >> 5, col = i & 31;
        s_idx[row * 33 + col] = idx_tab[(size_t)o0 * NACT + i];
        s_w  [row * 33 + col] = w_tab  [(size_t)o0 * NACT + i];
    }
    if (t < 16) s_bias[t] = bias[o0 + t];
    __syncthreads();

    const float* xb = xT + b;                 // row i lives at xb[i*BATCH]

    float acc[4];
    #pragma unroll
    for (int j = 0; j < 4; ++j) {
        const int o = oq * 4 + j;
        const int*   ip = s_idx + o * 33;
        const float* wp = s_w   + o * 33;
        float a0 = 0.f, a1 = 0.f;
        #pragma unroll
        for (int k = 0; k < NACT; k += 2) {
            a0 = fmaf(wp[k],   xb[(size_t)ip[k]   * BATCH], a0);
            a1 = fmaf(wp[k+1], xb[(size_t)ip[k+1] * BATCH], a1);
        }
        acc[j] = (a0 + a1) - s_bias[o];
    }

    f32x4 r = { acc[0], acc[1], acc[2], acc[3] };
    __builtin_nontemporal_store(r, (f32x4*)(out + (size_t)b * OUT_DIM + o0 + oq * 4));
}

// ---------------------------------------------------------------------------
// Fallback A (ws >= table only): gathers from x directly (uncoalesced, correct).
// ---------------------------------------------------------------------------
__global__ __launch_bounds__(256)
void spmm_noT_kernel(const float* __restrict__ x,
                     const int*   __restrict__ idx_tab,
                     const float* __restrict__ w_tab,
                     const float* __restrict__ bias,
                     float*       __restrict__ out) {
    const int t   = threadIdx.x;
    const int bid = blockIdx.x;           // 4096 blocks
    const int slab = bid >> 8;
    const int ot   = bid & 255;
    const int o0   = ot * 16;
    const int b    = slab * 256 + t;

    float acc[16];
    #pragma unroll 1
    for (int o = 0; o < 16; ++o) {
        const int*   ip = idx_tab + (size_t)(o0 + o) * NACT;
        const float* wp = w_tab   + (size_t)(o0 + o) * NACT;
        float a = 0.f;
        for (int k = 0; k < NACT; ++k)
            a = fmaf(wp[k], x[(size_t)b * IN_DIM + ip[k]], a);
        acc[o] = a - bias[o0 + o];
    }
    float* op = out + (size_t)b * OUT_DIM + o0;
    #pragma unroll
    for (int q = 0; q < 4; ++q) {
        float4 r; r.x = acc[q*4+0]; r.y = acc[q*4+1];
                  r.z = acc[q*4+2]; r.w = acc[q*4+3];
        *(float4*)(op + q*4) = r;
    }
}

// ---------------------------------------------------------------------------
// Fallback B (tiny ws): block per output row; inline compress into LDS.
// ---------------------------------------------------------------------------
__global__ __launch_bounds__(256)
void naive_kernel(const float* __restrict__ x,
                  const float* __restrict__ weight,
                  const float* __restrict__ bias,
                  const int*   __restrict__ mask,
                  float*       __restrict__ out) {
    const int o = blockIdx.x;
    const int t = threadIdx.x;
    __shared__ int   scan[256];
    __shared__ int   sidx[NACT];
    __shared__ float sw[NACT];

    const int* mrow = mask + (size_t)o * IN_DIM;
    const int  base = t * 16;
    int c = 0;
    #pragma unroll
    for (int j = 0; j < 16; ++j) c += (mrow[base + j] != 0);
    scan[t] = c;
    __syncthreads();
    for (int off = 1; off < 256; off <<= 1) {
        int add = (t >= off) ? scan[t - off] : 0;
        __syncthreads();
        scan[t] += add;
        __syncthreads();
    }
    int pos = scan[t] - c;
    for (int j = 0; j < 16; ++j) {
        if (mrow[base + j] != 0) {
            sidx[pos] = base + j;
            sw[pos]   = weight[(size_t)o * IN_DIM + base + j];
            ++pos;
        }
    }
    __syncthreads();
    const float bo = bias[o];
    for (int b = t; b < BATCH; b += 256) {
        float a = 0.f;
        #pragma unroll
        for (int k = 0; k < NACT; ++k)
            a = fmaf(sw[k], x[(size_t)b * IN_DIM + sidx[k]], a);
        out[(size_t)b * OUT_DIM + o] = a - bo;
    }
}

// ---------------------------------------------------------------------------
extern "C" void kernel_launch(void* const* d_in, const int* in_sizes, int n_in,
                              void* d_out, int out_size, void* d_ws, size_t ws_size,
                              hipStream_t stream) {
    const float* x      = (const float*)d_in[0];
    const float* weight = (const float*)d_in[1];
    const float* bias   = (const float*)d_in[2];
    const int*   mask   = (const int*)  d_in[3];
    float* out = (float*)d_out;

    const size_t TAB_BYTES  = (size_t)OUT_DIM * NACT * (sizeof(int) + sizeof(float)); // 1 MB
    const size_t XT_BYTES   = (size_t)IN_DIM * BATCH * sizeof(float);                 // 64 MB
    const size_t NEED_FULL  = TAB_BYTES + XT_BYTES;

    if (ws_size >= NEED_FULL) {
        int*   idx_tab = (int*)d_ws;
        float* w_tab   = (float*)((char*)d_ws + (size_t)OUT_DIM * NACT * sizeof(int));
        float* xT      = (float*)((char*)d_ws + TAB_BYTES);

        prep_kernel<<<OUT_DIM + (BATCH/64)*(IN_DIM/64), 256, 0, stream>>>(
            weight, mask, x, idx_tab, w_tab, xT);
        spmm_kernel<<<16384, 256, 0, stream>>>(xT, idx_tab, w_tab, bias, out);
    } else if (ws_size >= TAB_BYTES) {
        int*   idx_tab = (int*)d_ws;
        float* w_tab   = (float*)((char*)d_ws + (size_t)OUT_DIM * NACT * sizeof(int));
        prep_kernel<<<OUT_DIM, 256, 0, stream>>>(
            weight, mask, x, idx_tab, w_tab, (float*)nullptr);
        spmm_noT_kernel<<<4096, 256, 0, stream>>>(x, idx_tab, w_tab, bias, out);
    } else {
        naive_kernel<<<OUT_DIM, 256, 0, stream>>>(x, weight, bias, mask, out);
    }
}

// Round 6
// 146.690 us; speedup vs baseline: 1.8368x; 1.8368x over previous
//
#include <hip/hip_runtime.h>
#include <stdint.h>

#define IN_DIM  4096
#define OUT_DIM 4096
#define BATCH   4096
#define NACT    32

typedef float f32x4 __attribute__((ext_vector_type(4)));

// ---------------------------------------------------------------------------
// Fused prep kernel (proven ~15us: inputs are L3-resident).
//   blocks [0, OUT_DIM)              : compress mask+weight -> idx/w tables
//   blocks [OUT_DIM, OUT_DIM+4096)   : transpose x -> xT (64x64 f32 tiles)
// ---------------------------------------------------------------------------
__global__ __launch_bounds__(256)
void prep_kernel(const float* __restrict__ weight,
                 const int*   __restrict__ mask,
                 const float* __restrict__ x,
                 int*         __restrict__ idx_tab,
                 float*       __restrict__ w_tab,
                 float*       __restrict__ xT) {
    __shared__ float tile[64][65];        // transpose tile; aliased as scan[]
    int* scan = (int*)&tile[0][0];
    const int t = threadIdx.x;

    if (blockIdx.x < OUT_DIM) {
        // ---- compress: one block per output row ----
        const int o = blockIdx.x;
        const int* mrow = mask + (size_t)o * IN_DIM;
        const int  base = t * 16;

        int m[16];
        const int4* m4 = (const int4*)(mrow + base);
        #pragma unroll
        for (int j = 0; j < 4; ++j) {
            int4 v = m4[j];
            m[j*4+0] = v.x; m[j*4+1] = v.y; m[j*4+2] = v.z; m[j*4+3] = v.w;
        }
        int c = 0;
        #pragma unroll
        for (int j = 0; j < 16; ++j) c += (m[j] != 0);

        scan[t] = c;
        __syncthreads();
        for (int off = 1; off < 256; off <<= 1) {
            int add = (t >= off) ? scan[t - off] : 0;
            __syncthreads();
            scan[t] += add;
            __syncthreads();
        }
        int pos = scan[t] - c;            // exclusive prefix
        for (int j = 0; j < 16; ++j) {
            if (m[j] != 0) {
                int idx = base + j;
                idx_tab[o * NACT + pos] = idx;
                w_tab [o * NACT + pos] = weight[(size_t)o * IN_DIM + idx];
                ++pos;
            }
        }
    } else {
        // ---- transpose: 64x64 tile ----
        const int q  = blockIdx.x - OUT_DIM;
        const int bi = q & 63;            // batch tile
        const int bj = q >> 6;            // in-dim tile
        {
            const int c  = (t & 15) * 4;
            const int r0 = t >> 4;
            #pragma unroll
            for (int p = 0; p < 4; ++p) {
                int r = r0 + p * 16;
                float4 v = *(const float4*)(x + (size_t)(bi*64 + r) * IN_DIM + bj*64 + c);
                tile[r][c+0] = v.x; tile[r][c+1] = v.y;
                tile[r][c+2] = v.z; tile[r][c+3] = v.w;
            }
        }
        __syncthreads();
        {
            const int b4 = (t & 15) * 4;
            const int j0 = t >> 4;
            #pragma unroll
            for (int p = 0; p < 4; ++p) {
                int j = j0 + p * 16;
                float4 v;
                v.x = tile[b4+0][j]; v.y = tile[b4+1][j];
                v.z = tile[b4+2][j]; v.w = tile[b4+3][j];
                *(float4*)(xT + (size_t)(bj*64 + j) * BATCH + bi*64 + b4) = v;
            }
        }
    }
}

// ---------------------------------------------------------------------------
// Main sparse matmul — round-3 compute geometry + round-5 store pattern.
// Thread = 1 batch x 16 consecutive outputs (acc[16] in VGPRs); the whole
// wave shares o at each step -> idx/w/bias loads are WAVE-UNIFORM s_loads
// (scalar cache, SGPR gather base; round-5's per-lane tables cost 2x).
// Gathers: 64 lanes read 256 contiguous bytes of one xT row (L2-resident
// 4 MB slab; nt stores keep the write stream from evicting it).
// Store: acc[16] restaged through LDS (column-major, stride-257 pad) so
// lanes 0-3 emit one FULL 64B line per f32x4 nt store (round-4's partial
// -line nt was 2.9x write amp; round 5 proved full-line nt = 70 MB).
// Grid = 16 slabs x 256 o-tiles; swizzle: each XCD sweeps o-tiles slab-major.
// ---------------------------------------------------------------------------
__global__ __launch_bounds__(256)
void spmm_kernel(const float* __restrict__ xT,
                 const int*   __restrict__ idx_tab,
                 const float* __restrict__ w_tab,
                 const float* __restrict__ bias,
                 float*       __restrict__ out) {
    const int t   = threadIdx.x;
    const int bid = blockIdx.x;           // 4096 blocks
    const int v    = (bid & 7) * 512 + (bid >> 3);   // bijective XCD swizzle
    const int slab = v >> 8;              // 0..15 (slab-major per XCD)
    const int ot   = v & 255;             // o-tile minor
    const int o0   = ot * 16;
    const int b    = slab * 256 + t;      // this thread's batch

    const float* xb = xT + b;             // row i lives at xb[i*BATCH]

    float acc[16];
    #pragma unroll 2
    for (int o = 0; o < 16; ++o) {
        const int*   ip = idx_tab + (size_t)(o0 + o) * NACT;   // wave-uniform
        const float* wp = w_tab   + (size_t)(o0 + o) * NACT;   // -> s_load
        float a0 = 0.f, a1 = 0.f;
        #pragma unroll
        for (int k = 0; k < NACT; k += 2) {
            a0 = fmaf(wp[k],   xb[(size_t)ip[k]   * BATCH], a0);
            a1 = fmaf(wp[k+1], xb[(size_t)ip[k+1] * BATCH], a1);
        }
        acc[o] = (a0 + a1) - bias[o0 + o];
    }

    // ---- restage through LDS for full-line nt stores ----
    __shared__ float L[16 * 257];         // column-major L[o][b_local], padded
    #pragma unroll
    for (int o = 0; o < 16; ++o) L[o * 257 + t] = acc[o];  // stride-1/wave: free
    __syncthreads();

    const int rr = t >> 2;                // row group
    const int c  = (t & 3) * 4;           // 16B sub-line
    #pragma unroll
    for (int p = 0; p < 4; ++p) {
        int r = rr + p * 64;              // batch-local row
        f32x4 rv = { L[(c+0)*257 + r], L[(c+1)*257 + r],
                     L[(c+2)*257 + r], L[(c+3)*257 + r] };
        __builtin_nontemporal_store(rv,
            (f32x4*)(out + (size_t)(slab*256 + r) * OUT_DIM + o0 + c));
    }
}

// ---------------------------------------------------------------------------
// Fallback A (ws >= table only): gathers from x directly (uncoalesced, correct).
// ---------------------------------------------------------------------------
__global__ __launch_bounds__(256)
void spmm_noT_kernel(const float* __restrict__ x,
                     const int*   __restrict__ idx_tab,
                     const float* __restrict__ w_tab,
                     const float* __restrict__ bias,
                     float*       __restrict__ out) {
    const int t   = threadIdx.x;
    const int bid = blockIdx.x;           // 4096 blocks
    const int slab = bid >> 8;
    const int ot   = bid & 255;
    const int o0   = ot * 16;
    const int b    = slab * 256 + t;

    float acc[16];
    #pragma unroll 1
    for (int o = 0; o < 16; ++o) {
        const int*   ip = idx_tab + (size_t)(o0 + o) * NACT;
        const float* wp = w_tab   + (size_t)(o0 + o) * NACT;
        float a = 0.f;
        for (int k = 0; k < NACT; ++k)
            a = fmaf(wp[k], x[(size_t)b * IN_DIM + ip[k]], a);
        acc[o] = a - bias[o0 + o];
    }
    float* op = out + (size_t)b * OUT_DIM + o0;
    #pragma unroll
    for (int q = 0; q < 4; ++q) {
        float4 r; r.x = acc[q*4+0]; r.y = acc[q*4+1];
                  r.z = acc[q*4+2]; r.w = acc[q*4+3];
        *(float4*)(op + q*4) = r;
    }
}

// ---------------------------------------------------------------------------
// Fallback B (tiny ws): block per output row; inline compress into LDS.
// ---------------------------------------------------------------------------
__global__ __launch_bounds__(256)
void naive_kernel(const float* __restrict__ x,
                  const float* __restrict__ weight,
                  const float* __restrict__ bias,
                  const int*   __restrict__ mask,
                  float*       __restrict__ out) {
    const int o = blockIdx.x;
    const int t = threadIdx.x;
    __shared__ int   scan[256];
    __shared__ int   sidx[NACT];
    __shared__ float sw[NACT];

    const int* mrow = mask + (size_t)o * IN_DIM;
    const int  base = t * 16;
    int c = 0;
    #pragma unroll
    for (int j = 0; j < 16; ++j) c += (mrow[base + j] != 0);
    scan[t] = c;
    __syncthreads();
    for (int off = 1; off < 256; off <<= 1) {
        int add = (t >= off) ? scan[t - off] : 0;
        __syncthreads();
        scan[t] += add;
        __syncthreads();
    }
    int pos = scan[t] - c;
    for (int j = 0; j < 16; ++j) {
        if (mrow[base + j] != 0) {
            sidx[pos] = base + j;
            sw[pos]   = weight[(size_t)o * IN_DIM + base + j];
            ++pos;
        }
    }
    __syncthreads();
    const float bo = bias[o];
    for (int b = t; b < BATCH; b += 256) {
        float a = 0.f;
        #pragma unroll
        for (int k = 0; k < NACT; ++k)
            a = fmaf(sw[k], x[(size_t)b * IN_DIM + sidx[k]], a);
        out[(size_t)b * OUT_DIM + o] = a - bo;
    }
}

// ---------------------------------------------------------------------------
extern "C" void kernel_launch(void* const* d_in, const int* in_sizes, int n_in,
                              void* d_out, int out_size, void* d_ws, size_t ws_size,
                              hipStream_t stream) {
    const float* x      = (const float*)d_in[0];
    const float* weight = (const float*)d_in[1];
    const float* bias   = (const float*)d_in[2];
    const int*   mask   = (const int*)  d_in[3];
    float* out = (float*)d_out;

    const size_t TAB_BYTES  = (size_t)OUT_DIM * NACT * (sizeof(int) + sizeof(float)); // 1 MB
    const size_t XT_BYTES   = (size_t)IN_DIM * BATCH * sizeof(float);                 // 64 MB
    const size_t NEED_FULL  = TAB_BYTES + XT_BYTES;

    if (ws_size >= NEED_FULL) {
        int*   idx_tab = (int*)d_ws;
        float* w_tab   = (float*)((char*)d_ws + (size_t)OUT_DIM * NACT * sizeof(int));
        float* xT      = (float*)((char*)d_ws + TAB_BYTES);

        prep_kernel<<<OUT_DIM + (BATCH/64)*(IN_DIM/64), 256, 0, stream>>>(
            weight, mask, x, idx_tab, w_tab, xT);
        spmm_kernel<<<4096, 256, 0, stream>>>(xT, idx_tab, w_tab, bias, out);
    } else if (ws_size >= TAB_BYTES) {
        int*   idx_tab = (int*)d_ws;
        float* w_tab   = (float*)((char*)d_ws + (size_t)OUT_DIM * NACT * sizeof(int));
        prep_kernel<<<OUT_DIM, 256, 0, stream>>>(
            weight, mask, x, idx_tab, w_tab, (float*)nullptr);
        spmm_noT_kernel<<<4096, 256, 0, stream>>>(x, idx_tab, w_tab, bias, out);
    } else {
        naive_kernel<<<OUT_DIM, 256, 0, stream>>>(x, weight, bias, mask, out);
    }
}

// Round 7
// 120.380 us; speedup vs baseline: 2.2383x; 1.2186x over previous
//
#include <hip/hip_runtime.h>
#include <stdint.h>

#define IN_DIM  4096
#define OUT_DIM 4096
#define BATCH   4096
#define NACT    32

typedef float          f32x4  __attribute__((ext_vector_type(4)));
typedef unsigned short u16x4  __attribute__((ext_vector_type(4)));

// round-to-nearest-even-ish f32 -> bf16 (RN halves quantization error vs trunc)
__device__ inline unsigned short f2bf(float f) {
    unsigned u = __float_as_uint(f);
    u += 0x7FFF + ((u >> 16) & 1);
    return (unsigned short)(u >> 16);
}

// ---------------------------------------------------------------------------
// Fused prep kernel.
//   blocks [0, OUT_DIM)              : compress mask+weight -> idx/w tables
//   blocks [OUT_DIM, OUT_DIM+4096)   : transpose x -> xT bf16 [IN_DIM][BATCH]
// ---------------------------------------------------------------------------
__global__ __launch_bounds__(256)
void prep_kernel(const float* __restrict__ weight,
                 const int*   __restrict__ mask,
                 const float* __restrict__ x,
                 int*         __restrict__ idx_tab,
                 float*       __restrict__ w_tab,
                 unsigned short* __restrict__ xT) {
    __shared__ float tile[64][65];        // transpose tile; aliased as scan[]
    int* scan = (int*)&tile[0][0];
    const int t = threadIdx.x;

    if (blockIdx.x < OUT_DIM) {
        // ---- compress: one block per output row ----
        const int o = blockIdx.x;
        const int* mrow = mask + (size_t)o * IN_DIM;
        const int  base = t * 16;

        int m[16];
        const int4* m4 = (const int4*)(mrow + base);
        #pragma unroll
        for (int j = 0; j < 4; ++j) {
            int4 v = m4[j];
            m[j*4+0] = v.x; m[j*4+1] = v.y; m[j*4+2] = v.z; m[j*4+3] = v.w;
        }
        int c = 0;
        #pragma unroll
        for (int j = 0; j < 16; ++j) c += (m[j] != 0);

        scan[t] = c;
        __syncthreads();
        for (int off = 1; off < 256; off <<= 1) {
            int add = (t >= off) ? scan[t - off] : 0;
            __syncthreads();
            scan[t] += add;
            __syncthreads();
        }
        int pos = scan[t] - c;            // exclusive prefix
        for (int j = 0; j < 16; ++j) {
            if (m[j] != 0) {
                int idx = base + j;
                idx_tab[o * NACT + pos] = idx;
                w_tab [o * NACT + pos] = weight[(size_t)o * IN_DIM + idx];
                ++pos;
            }
        }
    } else {
        // ---- transpose + bf16 quantize: 64x64 tile ----
        const int q  = blockIdx.x - OUT_DIM;
        const int bi = q & 63;            // batch tile
        const int bj = q >> 6;            // in-dim tile
        {
            const int c  = (t & 15) * 4;
            const int r0 = t >> 4;
            #pragma unroll
            for (int p = 0; p < 4; ++p) {
                int r = r0 + p * 16;
                float4 v = *(const float4*)(x + (size_t)(bi*64 + r) * IN_DIM + bj*64 + c);
                tile[r][c+0] = v.x; tile[r][c+1] = v.y;
                tile[r][c+2] = v.z; tile[r][c+3] = v.w;
            }
        }
        __syncthreads();
        {
            const int b4 = (t & 15) * 4;
            const int j0 = t >> 4;
            #pragma unroll
            for (int p = 0; p < 4; ++p) {
                int j = j0 + p * 16;
                u16x4 v = { f2bf(tile[b4+0][j]), f2bf(tile[b4+1][j]),
                            f2bf(tile[b4+2][j]), f2bf(tile[b4+3][j]) };
                *(u16x4*)(xT + (size_t)(bj*64 + j) * BATCH + bi*64 + b4) = v;
            }
        }
    }
}

// ---------------------------------------------------------------------------
// Main sparse matmul.
// Thread = 1 batch x 16 consecutive outputs (acc[16]); o is wave-uniform ->
// idx/w/bias are scalar s_loads. Gathers: bf16 xT row, wave reads 128 B
// (2 full lines). Slab = 256 batches x 4096 rows x 2B = 2 MB -> resident in
// 4 MB XCD L2 WITH slack (round-6's f32 slab was exactly 4 MB -> 3x refill).
// nt stores keep the write stream out of L2.
// Store: acc[16] restaged via LDS L[b_local][o] stride-17 (write banks
// 17t mod 32 = 2-way free; read banks 17r+4q+j = exactly 2-way free), then
// lanes 0-3 emit one FULL 64B line per f32x4 nt store.
// Grid = 16 slabs x 256 o-tiles; swizzle: each XCD sweeps o-tiles slab-major.
// ---------------------------------------------------------------------------
__global__ __launch_bounds__(256)
void spmm_kernel(const unsigned short* __restrict__ xT,
                 const int*   __restrict__ idx_tab,
                 const float* __restrict__ w_tab,
                 const float* __restrict__ bias,
                 float*       __restrict__ out) {
    const int t   = threadIdx.x;
    const int bid = blockIdx.x;           // 4096 blocks
    const int v    = (bid & 7) * 512 + (bid >> 3);   // bijective XCD swizzle
    const int slab = v >> 8;              // 0..15 (slab-major per XCD)
    const int ot   = v & 255;             // o-tile minor
    const int o0   = ot * 16;
    const int b    = slab * 256 + t;      // this thread's batch

    const unsigned short* xb = xT + b;    // row i lives at xb[i*BATCH]

    float acc[16];
    #pragma unroll 2
    for (int o = 0; o < 16; ++o) {
        const int*   ip = idx_tab + (size_t)(o0 + o) * NACT;   // wave-uniform
        const float* wp = w_tab   + (size_t)(o0 + o) * NACT;   // -> s_load
        float a0 = 0.f, a1 = 0.f;
        #pragma unroll
        for (int k = 0; k < NACT; k += 2) {
            float x0 = __uint_as_float((unsigned)xb[(size_t)ip[k]   * BATCH] << 16);
            float x1 = __uint_as_float((unsigned)xb[(size_t)ip[k+1] * BATCH] << 16);
            a0 = fmaf(wp[k],   x0, a0);
            a1 = fmaf(wp[k+1], x1, a1);
        }
        acc[o] = (a0 + a1) - bias[o0 + o];
    }

    // ---- restage through LDS for full-line nt stores ----
    __shared__ float L[256 * 17];         // L[b_local][o], stride 17
    #pragma unroll
    for (int o = 0; o < 16; ++o) L[t * 17 + o] = acc[o];   // 2-way: free
    __syncthreads();

    const int rr = t >> 2;                // row group
    const int c  = (t & 3) * 4;           // 16B sub-line (output offset)
    #pragma unroll
    for (int p = 0; p < 4; ++p) {
        int r = rr + p * 64;              // batch-local row
        f32x4 rv = { L[r*17 + c+0], L[r*17 + c+1],
                     L[r*17 + c+2], L[r*17 + c+3] };
        __builtin_nontemporal_store(rv,
            (f32x4*)(out + (size_t)(slab*256 + r) * OUT_DIM + o0 + c));
    }
}

// ---------------------------------------------------------------------------
// Fallback A (ws >= table only): gathers from x directly (uncoalesced, correct).
// ---------------------------------------------------------------------------
__global__ __launch_bounds__(256)
void spmm_noT_kernel(const float* __restrict__ x,
                     const int*   __restrict__ idx_tab,
                     const float* __restrict__ w_tab,
                     const float* __restrict__ bias,
                     float*       __restrict__ out) {
    const int t   = threadIdx.x;
    const int bid = blockIdx.x;           // 4096 blocks
    const int slab = bid >> 8;
    const int ot   = bid & 255;
    const int o0   = ot * 16;
    const int b    = slab * 256 + t;

    float acc[16];
    #pragma unroll 1
    for (int o = 0; o < 16; ++o) {
        const int*   ip = idx_tab + (size_t)(o0 + o) * NACT;
        const float* wp = w_tab   + (size_t)(o0 + o) * NACT;
        float a = 0.f;
        for (int k = 0; k < NACT; ++k)
            a = fmaf(wp[k], x[(size_t)b * IN_DIM + ip[k]], a);
        acc[o] = a - bias[o0 + o];
    }
    float* op = out + (size_t)b * OUT_DIM + o0;
    #pragma unroll
    for (int q = 0; q < 4; ++q) {
        float4 r; r.x = acc[q*4+0]; r.y = acc[q*4+1];
                  r.z = acc[q*4+2]; r.w = acc[q*4+3];
        *(float4*)(op + q*4) = r;
    }
}

// ---------------------------------------------------------------------------
// Fallback B (tiny ws): block per output row; inline compress into LDS.
// ---------------------------------------------------------------------------
__global__ __launch_bounds__(256)
void naive_kernel(const float* __restrict__ x,
                  const float* __restrict__ weight,
                  const float* __restrict__ bias,
                  const int*   __restrict__ mask,
                  float*       __restrict__ out) {
    const int o = blockIdx.x;
    const int t = threadIdx.x;
    __shared__ int   scan[256];
    __shared__ int   sidx[NACT];
    __shared__ float sw[NACT];

    const int* mrow = mask + (size_t)o * IN_DIM;
    const int  base = t * 16;
    int c = 0;
    #pragma unroll
    for (int j = 0; j < 16; ++j) c += (mrow[base + j] != 0);
    scan[t] = c;
    __syncthreads();
    for (int off = 1; off < 256; off <<= 1) {
        int add = (t >= off) ? scan[t - off] : 0;
        __syncthreads();
        scan[t] += add;
        __syncthreads();
    }
    int pos = scan[t] - c;
    for (int j = 0; j < 16; ++j) {
        if (mrow[base + j] != 0) {
            sidx[pos] = base + j;
            sw[pos]   = weight[(size_t)o * IN_DIM + base + j];
            ++pos;
        }
    }
    __syncthreads();
    const float bo = bias[o];
    for (int b = t; b < BATCH; b += 256) {
        float a = 0.f;
        #pragma unroll
        for (int k = 0; k < NACT; ++k)
            a = fmaf(sw[k], x[(size_t)b * IN_DIM + sidx[k]], a);
        out[(size_t)b * OUT_DIM + o] = a - bo;
    }
}

// ---------------------------------------------------------------------------
extern "C" void kernel_launch(void* const* d_in, const int* in_sizes, int n_in,
                              void* d_out, int out_size, void* d_ws, size_t ws_size,
                              hipStream_t stream) {
    const float* x      = (const float*)d_in[0];
    const float* weight = (const float*)d_in[1];
    const float* bias   = (const float*)d_in[2];
    const int*   mask   = (const int*)  d_in[3];
    float* out = (float*)d_out;

    const size_t TAB_BYTES  = (size_t)OUT_DIM * NACT * (sizeof(int) + sizeof(float)); // 1 MB
    const size_t XT_BYTES   = (size_t)IN_DIM * BATCH * sizeof(unsigned short);        // 32 MB
    const size_t NEED_FULL  = TAB_BYTES + XT_BYTES;

    if (ws_size >= NEED_FULL) {
        int*   idx_tab = (int*)d_ws;
        float* w_tab   = (float*)((char*)d_ws + (size_t)OUT_DIM * NACT * sizeof(int));
        unsigned short* xT = (unsigned short*)((char*)d_ws + TAB_BYTES);

        prep_kernel<<<OUT_DIM + (BATCH/64)*(IN_DIM/64), 256, 0, stream>>>(
            weight, mask, x, idx_tab, w_tab, xT);
        spmm_kernel<<<4096, 256, 0, stream>>>(xT, idx_tab, w_tab, bias, out);
    } else if (ws_size >= TAB_BYTES) {
        int*   idx_tab = (int*)d_ws;
        float* w_tab   = (float*)((char*)d_ws + (size_t)OUT_DIM * NACT * sizeof(int));
        prep_kernel<<<OUT_DIM, 256, 0, stream>>>(
            weight, mask, x, idx_tab, w_tab, (unsigned short*)nullptr);
        spmm_noT_kernel<<<4096, 256, 0, stream>>>(x, idx_tab, w_tab, bias, out);
    } else {
        naive_kernel<<<OUT_DIM, 256, 0, stream>>>(x, weight, bias, mask, out);
    }
}

// Round 8
// 95.510 us; speedup vs baseline: 2.8211x; 1.2604x over previous
//
#include <hip/hip_runtime.h>
#include <stdint.h>

#define IN_DIM  4096
#define OUT_DIM 4096
#define BATCH   4096
#define NACT    32

typedef float          f32x4  __attribute__((ext_vector_type(4)));
typedef unsigned short u16x4  __attribute__((ext_vector_type(4)));

// round-to-nearest f32 -> bf16
__device__ inline unsigned short f2bf(float f) {
    unsigned u = __float_as_uint(f);
    u += 0x7FFF + ((u >> 16) & 1);
    return (unsigned short)(u >> 16);
}

// ---------------------------------------------------------------------------
// Fused prep kernel.
//   blocks [0, OUT_DIM)              : compress mask+weight -> idx/w tables
//   blocks [OUT_DIM, OUT_DIM+4096)   : transpose x -> xT bf16 [IN_DIM][BATCH]
// ---------------------------------------------------------------------------
__global__ __launch_bounds__(256)
void prep_kernel(const float* __restrict__ weight,
                 const int*   __restrict__ mask,
                 const float* __restrict__ x,
                 int*         __restrict__ idx_tab,
                 float*       __restrict__ w_tab,
                 unsigned short* __restrict__ xT) {
    __shared__ float tile[64][65];        // transpose tile; aliased as scan[]
    int* scan = (int*)&tile[0][0];
    const int t = threadIdx.x;

    if (blockIdx.x < OUT_DIM) {
        // ---- compress: one block per output row ----
        const int o = blockIdx.x;
        const int* mrow = mask + (size_t)o * IN_DIM;
        const int  base = t * 16;

        int m[16];
        const int4* m4 = (const int4*)(mrow + base);
        #pragma unroll
        for (int j = 0; j < 4; ++j) {
            int4 v = m4[j];
            m[j*4+0] = v.x; m[j*4+1] = v.y; m[j*4+2] = v.z; m[j*4+3] = v.w;
        }
        int c = 0;
        #pragma unroll
        for (int j = 0; j < 16; ++j) c += (m[j] != 0);

        scan[t] = c;
        __syncthreads();
        for (int off = 1; off < 256; off <<= 1) {
            int add = (t >= off) ? scan[t - off] : 0;
            __syncthreads();
            scan[t] += add;
            __syncthreads();
        }
        int pos = scan[t] - c;            // exclusive prefix
        for (int j = 0; j < 16; ++j) {
            if (m[j] != 0) {
                int idx = base + j;
                idx_tab[o * NACT + pos] = idx;
                w_tab [o * NACT + pos] = weight[(size_t)o * IN_DIM + idx];
                ++pos;
            }
        }
    } else {
        // ---- transpose + bf16 quantize: 64x64 tile ----
        const int q  = blockIdx.x - OUT_DIM;
        const int bi = q & 63;            // batch tile
        const int bj = q >> 6;            // in-dim tile
        {
            const int c  = (t & 15) * 4;
            const int r0 = t >> 4;
            #pragma unroll
            for (int p = 0; p < 4; ++p) {
                int r = r0 + p * 16;
                float4 v = *(const float4*)(x + (size_t)(bi*64 + r) * IN_DIM + bj*64 + c);
                tile[r][c+0] = v.x; tile[r][c+1] = v.y;
                tile[r][c+2] = v.z; tile[r][c+3] = v.w;
            }
        }
        __syncthreads();
        {
            const int b4 = (t & 15) * 4;
            const int j0 = t >> 4;
            #pragma unroll
            for (int p = 0; p < 4; ++p) {
                int j = j0 + p * 16;
                u16x4 v = { f2bf(tile[b4+0][j]), f2bf(tile[b4+1][j]),
                            f2bf(tile[b4+2][j]), f2bf(tile[b4+3][j]) };
                *(u16x4*)(xT + (size_t)(bj*64 + j) * BATCH + bi*64 + b4) = v;
            }
        }
    }
}

// ---------------------------------------------------------------------------
// Main sparse matmul.
// Block = 128 threads; thread t = batches (2t, 2t+1) x 16 outputs.
// Slab stays 256 batches x 4096 rows x 2B = 2 MB (proven L2-resident,
// FETCH ~= compulsory in round 7). Gathers are u16x2 (dword) loads: one
// load + <<16 / &0xFFFF0000 serves TWO batches -> wave-load count and
// per-element address VALU halve vs round 7 (the measured stall source).
// o is wave-uniform -> idx/w/bias stay scalar s_loads.
// Store: acc restaged via LDS L[b_local][o] stride-17 (2-way = free), then
// lanes 0-3 emit one FULL 64B line per f32x4 nt store (nt keeps the write
// stream out of L2; full lines avoid round-4's write amplification).
// Grid = 16 slabs x 256 o-tiles; swizzle: each XCD sweeps o-tiles slab-major.
// ---------------------------------------------------------------------------
__global__ __launch_bounds__(128)
void spmm_kernel(const unsigned short* __restrict__ xT,
                 const int*   __restrict__ idx_tab,
                 const float* __restrict__ w_tab,
                 const float* __restrict__ bias,
                 float*       __restrict__ out) {
    const int t   = threadIdx.x;          // 0..127
    const int bid = blockIdx.x;           // 4096 blocks
    const int v    = (bid & 7) * 512 + (bid >> 3);   // bijective XCD swizzle
    const int slab = v >> 8;              // 0..15 (slab-major per XCD)
    const int ot   = v & 255;             // o-tile minor
    const int o0   = ot * 16;
    const int b0   = slab * 256;          // slab batch base
    const int bl   = t * 2;               // batch-local (even)

    const unsigned short* xb = xT + b0 + bl;   // u16x2 at xb[i*BATCH]

    float acc0[16], acc1[16];
    #pragma unroll 2
    for (int o = 0; o < 16; ++o) {
        const int*   ip = idx_tab + (size_t)(o0 + o) * NACT;   // wave-uniform
        const float* wp = w_tab   + (size_t)(o0 + o) * NACT;   // -> s_load
        float a00 = 0.f, a01 = 0.f, a10 = 0.f, a11 = 0.f;
        #pragma unroll
        for (int k = 0; k < NACT; k += 2) {
            unsigned u0 = *(const unsigned*)(xb + (size_t)ip[k]   * BATCH);
            unsigned u1 = *(const unsigned*)(xb + (size_t)ip[k+1] * BATCH);
            float x00 = __uint_as_float(u0 << 16);          // batch bl
            float x01 = __uint_as_float(u0 & 0xFFFF0000u);  // batch bl+1
            float x10 = __uint_as_float(u1 << 16);
            float x11 = __uint_as_float(u1 & 0xFFFF0000u);
            a00 = fmaf(wp[k],   x00, a00);
            a01 = fmaf(wp[k],   x01, a01);
            a10 = fmaf(wp[k+1], x10, a10);
            a11 = fmaf(wp[k+1], x11, a11);
        }
        const float bo = bias[o0 + o];
        acc0[o] = (a00 + a10) - bo;
        acc1[o] = (a01 + a11) - bo;
    }

    // ---- restage through LDS for full-line nt stores ----
    __shared__ float L[256 * 17];         // L[b_local][o], stride 17
    #pragma unroll
    for (int o = 0; o < 16; ++o) {
        L[(bl + 0) * 17 + o] = acc0[o];   // banks 2t+o mod 32: 2-way = free
        L[(bl + 1) * 17 + o] = acc1[o];
    }
    __syncthreads();

    const int rr = t >> 2;                // 0..31
    const int c  = (t & 3) * 4;           // 16B sub-line (output offset)
    #pragma unroll
    for (int p = 0; p < 8; ++p) {
        int r = rr + p * 32;              // batch-local row 0..255
        f32x4 rv = { L[r*17 + c+0], L[r*17 + c+1],
                     L[r*17 + c+2], L[r*17 + c+3] };
        __builtin_nontemporal_store(rv,
            (f32x4*)(out + (size_t)(b0 + r) * OUT_DIM + o0 + c));
    }
}

// ---------------------------------------------------------------------------
// Fallback A (ws >= table only): gathers from x directly (uncoalesced, correct).
// ---------------------------------------------------------------------------
__global__ __launch_bounds__(256)
void spmm_noT_kernel(const float* __restrict__ x,
                     const int*   __restrict__ idx_tab,
                     const float* __restrict__ w_tab,
                     const float* __restrict__ bias,
                     float*       __restrict__ out) {
    const int t   = threadIdx.x;
    const int bid = blockIdx.x;           // 4096 blocks
    const int slab = bid >> 8;
    const int ot   = bid & 255;
    const int o0   = ot * 16;
    const int b    = slab * 256 + t;

    float acc[16];
    #pragma unroll 1
    for (int o = 0; o < 16; ++o) {
        const int*   ip = idx_tab + (size_t)(o0 + o) * NACT;
        const float* wp = w_tab   + (size_t)(o0 + o) * NACT;
        float a = 0.f;
        for (int k = 0; k < NACT; ++k)
            a = fmaf(wp[k], x[(size_t)b * IN_DIM + ip[k]], a);
        acc[o] = a - bias[o0 + o];
    }
    float* op = out + (size_t)b * OUT_DIM + o0;
    #pragma unroll
    for (int q = 0; q < 4; ++q) {
        float4 r; r.x = acc[q*4+0]; r.y = acc[q*4+1];
                  r.z = acc[q*4+2]; r.w = acc[q*4+3];
        *(float4*)(op + q*4) = r;
    }
}

// ---------------------------------------------------------------------------
// Fallback B (tiny ws): block per output row; inline compress into LDS.
// ---------------------------------------------------------------------------
__global__ __launch_bounds__(256)
void naive_kernel(const float* __restrict__ x,
                  const float* __restrict__ weight,
                  const float* __restrict__ bias,
                  const int*   __restrict__ mask,
                  float*       __restrict__ out) {
    const int o = blockIdx.x;
    const int t = threadIdx.x;
    __shared__ int   scan[256];
    __shared__ int   sidx[NACT];
    __shared__ float sw[NACT];

    const int* mrow = mask + (size_t)o * IN_DIM;
    const int  base = t * 16;
    int c = 0;
    #pragma unroll
    for (int j = 0; j < 16; ++j) c += (mrow[base + j] != 0);
    scan[t] = c;
    __syncthreads();
    for (int off = 1; off < 256; off <<= 1) {
        int add = (t >= off) ? scan[t - off] : 0;
        __syncthreads();
        scan[t] += add;
        __syncthreads();
    }
    int pos = scan[t] - c;
    for (int j = 0; j < 16; ++j) {
        if (mrow[base + j] != 0) {
            sidx[pos] = base + j;
            sw[pos]   = weight[(size_t)o * IN_DIM + base + j];
            ++pos;
        }
    }
    __syncthreads();
    const float bo = bias[o];
    for (int b = t; b < BATCH; b += 256) {
        float a = 0.f;
        #pragma unroll
        for (int k = 0; k < NACT; ++k)
            a = fmaf(sw[k], x[(size_t)b * IN_DIM + sidx[k]], a);
        out[(size_t)b * OUT_DIM + o] = a - bo;
    }
}

// ---------------------------------------------------------------------------
extern "C" void kernel_launch(void* const* d_in, const int* in_sizes, int n_in,
                              void* d_out, int out_size, void* d_ws, size_t ws_size,
                              hipStream_t stream) {
    const float* x      = (const float*)d_in[0];
    const float* weight = (const float*)d_in[1];
    const float* bias   = (const float*)d_in[2];
    const int*   mask   = (const int*)  d_in[3];
    float* out = (float*)d_out;

    const size_t TAB_BYTES  = (size_t)OUT_DIM * NACT * (sizeof(int) + sizeof(float)); // 1 MB
    const size_t XT_BYTES   = (size_t)IN_DIM * BATCH * sizeof(unsigned short);        // 32 MB
    const size_t NEED_FULL  = TAB_BYTES + XT_BYTES;

    if (ws_size >= NEED_FULL) {
        int*   idx_tab = (int*)d_ws;
        float* w_tab   = (float*)((char*)d_ws + (size_t)OUT_DIM * NACT * sizeof(int));
        unsigned short* xT = (unsigned short*)((char*)d_ws + TAB_BYTES);

        prep_kernel<<<OUT_DIM + (BATCH/64)*(IN_DIM/64), 256, 0, stream>>>(
            weight, mask, x, idx_tab, w_tab, xT);
        spmm_kernel<<<4096, 128, 0, stream>>>(xT, idx_tab, w_tab, bias, out);
    } else if (ws_size >= TAB_BYTES) {
        int*   idx_tab = (int*)d_ws;
        float* w_tab   = (float*)((char*)d_ws + (size_t)OUT_DIM * NACT * sizeof(int));
        prep_kernel<<<OUT_DIM, 256, 0, stream>>>(
            weight, mask, x, idx_tab, w_tab, (unsigned short*)nullptr);
        spmm_noT_kernel<<<4096, 256, 0, stream>>>(x, idx_tab, w_tab, bias, out);
    } else {
        naive_kernel<<<OUT_DIM, 256, 0, stream>>>(x, weight, bias, mask, out);
    }
}